// Round 5
// baseline (573.396 us; speedup 1.0000x reference)
//
#include <hip/hip_runtime.h>
#include <hip/hip_bf16.h>

// Problem constants (fixed by reference setup_inputs):
//   K3=27, PAIRS_PER_K=131072 (=2^17), N_VOX=262144 (=2^18), C_IN=C_OUT=32
//   M = 3,538,944 pairs. out = [262144][32] fp32.
//
// R1: 113M fp32 atomics = 5.9ms. R2: per-thread LDS weight reads = 3x FMA
// floor. R3: scalar gather latency-bound (770us). R4: MFMA gather correct but
// latency-bound (312us: MfmaUtil 1.9%, VALUBusy 19% -> 80% stall on two
// serial load chains). R5: software-pipeline both loops (probes up-front,
// distance-4 row prefetch, flattened overflow with lane-preloaded entries).

#define N_VOX    262144
#define LOG2_NV  18
#define C_CH     32
#define K3       27
#define LOG2_PPK 17
#define BLOCK    256
#define FLAG_FIN 0x40000000
#define ECAP     4096

typedef __attribute__((ext_vector_type(8))) short bf16x8;
typedef __attribute__((ext_vector_type(4))) float f32x4;

__device__ __forceinline__ unsigned short f2bf(float f) {
  union { __hip_bfloat16 h; unsigned short u; } cv;
  cv.h = __float2bfloat16(f);
  return cv.u;
}

// ---------------------------------------------------------------------------
// Pass A: last-writer-wins claim (plain stores).
__global__ __launch_bounds__(BLOCK) void passA_kernel(
    const int2* __restrict__ nbmap, int* __restrict__ T, int M) {
  int p = blockIdx.x * BLOCK + threadIdx.x;
  if (p >= M) return;
  int2 nb = nbmap[p];
  int k = p >> LOG2_PPK;
  T[(k << LOG2_NV) + nb.y] = p;
}

// Pass B: winners finalize (FLAG|in_idx); losers -> per-voxel overflow list;
// list overflow -> emergency list.
__global__ __launch_bounds__(BLOCK) void passB_kernel(
    const int2* __restrict__ nbmap, int* __restrict__ T,
    int* __restrict__ ovf_cnt, int* __restrict__ ovf, int S2,
    int* __restrict__ ecnt, int2* __restrict__ elist, int M) {
  int p = blockIdx.x * BLOCK + threadIdx.x;
  if (p >= M) return;
  int2 nb = nbmap[p];
  int k = p >> LOG2_PPK;
  int idx = (k << LOG2_NV) + nb.y;
  if (T[idx] == p) {
    T[idx] = FLAG_FIN | nb.x;                 // in_idx < 2^18
  } else {
    int pos = atomicAdd(&ovf_cnt[nb.y], 1);
    if (pos < S2) {
      ovf[(pos << LOG2_NV) + nb.y] = (k << LOG2_NV) | nb.x;
    } else {
      int ep = atomicAdd(ecnt, 1);
      if (ep < ECAP) elist[ep] = make_int2(nb.y, (k << LOG2_NV) | nb.x);
    }
  }
}

// ---------------------------------------------------------------------------
// B-fragment prep: W pre-permuted into mfma_16x16x32 B-operand lane layout
// (mirror of verified A layout A[m=lane&15][k=quad*8+j], m89/m91).
__global__ __launch_bounds__(BLOCK) void bf_prep_kernel(
    const float* __restrict__ kernel_w, unsigned short* __restrict__ Bf) {
  int tid = blockIdx.x * BLOCK + threadIdx.x;
  if (tid >= K3 * 2 * 64) return;
  int lane = tid & 63;
  int kc = tid >> 6;
  int k = kc >> 1, t = kc & 1;
  int i0 = (lane >> 4) * 8;
  int c = t * 16 + (lane & 15);
  union { unsigned short u[8]; uint4 v; } pk;
#pragma unroll
  for (int j = 0; j < 8; ++j)
    pk.u[j] = f2bf(kernel_w[(k << 10) + (i0 + j) * C_CH + c]);
  ((uint4*)Bf)[tid] = pk.v;
}

// ---------------------------------------------------------------------------
// MFMA gather, software-pipelined. Wave = 16 voxels.
__global__ __launch_bounds__(BLOCK) void gather_mfma_kernel(
    const float* __restrict__ in_feature,
    const float* __restrict__ kernel_w,
    const float* __restrict__ bias,
    const int* __restrict__ T,
    const int* __restrict__ ovf_cnt,
    const int* __restrict__ ovf,
    const unsigned short* __restrict__ Bf,
    float* __restrict__ out, int S2) {
  __shared__ float aux[4][16][33];            // +1 pad: conflict-free merge
  const int wv = threadIdx.x >> 6;
  const int lane = threadIdx.x & 63;
  float* auxw = &aux[wv][0][0];
  for (int i = lane; i < 16 * 33; i += 64) auxw[i] = 0.0f;

  const int vb = (blockIdx.x * 4 + wv) * 16;
  const int r16 = lane & 15;
  const int quad = lane >> 4;
  const int v = vb + r16;

  f32x4 acc0 = {0.f, 0.f, 0.f, 0.f};
  f32x4 acc1 = {0.f, 0.f, 0.f, 0.f};
  const uint4* bfp = (const uint4*)Bf;

  // ---- all 27 probes up front: one memory round trip ----
  int tv[K3];
#pragma unroll
  for (int k = 0; k < K3; ++k) tv[k] = T[(k << LOG2_NV) + v];

  // ---- distance-4 row pipeline; loads unconditional (invalid -> row 0) ----
  float4 rf[4][2];
#pragma unroll
  for (int d = 0; d < 4; ++d) {
    int t = tv[d];
    int in = (t >= 0) ? (t & 0x3FFFF) : 0;
    const float4* ap =
        (const float4*)(in_feature + (in << 5) + (quad << 3));
    rf[d][0] = ap[0];
    rf[d][1] = ap[1];
  }

#pragma unroll
  for (int k = 0; k < K3; ++k) {
    const int buf = k & 3;
    float4 f0 = rf[buf][0], f1 = rf[buf][1];
    if (k + 4 < K3) {                          // constant under full unroll
      int t2 = tv[k + 4];
      int in2 = (t2 >= 0) ? (t2 & 0x3FFFF) : 0;
      const float4* ap =
          (const float4*)(in_feature + (in2 << 5) + (quad << 3));
      rf[buf][0] = ap[0];
      rf[buf][1] = ap[1];
    }
    bf16x8 a;
    a[0] = (short)f2bf(f0.x); a[1] = (short)f2bf(f0.y);
    a[2] = (short)f2bf(f0.z); a[3] = (short)f2bf(f0.w);
    a[4] = (short)f2bf(f1.x); a[5] = (short)f2bf(f1.y);
    a[6] = (short)f2bf(f1.z); a[7] = (short)f2bf(f1.w);
    if (tv[k] < 0) a = (bf16x8)0;              // 4x v_cndmask on packed
    uint4 raw0 = bfp[(k * 2 + 0) * 64 + lane];
    uint4 raw1 = bfp[(k * 2 + 1) * 64 + lane];
    bf16x8 b0 = *reinterpret_cast<const bf16x8*>(&raw0);
    bf16x8 b1 = *reinterpret_cast<const bf16x8*>(&raw1);
    acc0 = __builtin_amdgcn_mfma_f32_16x16x32_bf16(a, b0, acc0, 0, 0, 0);
    acc1 = __builtin_amdgcn_mfma_f32_16x16x32_bf16(a, b1, acc1, 0, 0, 0);
  }

  // ---- overflow: flattened, lane-preloaded entries, distance-2 rows ----
  const int c32 = lane & 31, h = lane >> 5;
  int nv = 0;
  if (lane < 16) {
    nv = ovf_cnt[vb + lane];
    if (nv > S2) nv = S2;
  }
  for (int base = 0; base < 16 * 15; base += 64) {
    // flat index LL -> (rL, jL) via 16-step scan (all lanes)
    int LL = base + lane;
    int acc = 0, rL = 0, jL = -1;
#pragma unroll
    for (int r = 0; r < 16; ++r) {
      int nr = __shfl(nv, r);
      if (jL < 0 && LL < acc + nr) { rL = r; jL = LL - acc; }
      acc += nr;
    }
    const int total = acc;
    if (base >= total) break;
    const int nb = (total - base < 64) ? (total - base) : 64;

    int eL = 0;
    if (jL >= 0) eL = ovf[(jL << LOG2_NV) + vb + rL];  // 1 trip, all entries

    float av[2][16];
#pragma unroll
    for (int d = 0; d < 2; ++d) {
      if (d < nb) {
        int e = __shfl(eL, d);
        const float* arow = in_feature + ((e & 0x3FFFF) << 5) + (h << 4);
#pragma unroll
        for (int i = 0; i < 16; ++i) av[d][i] = arow[i];
      }
    }
#pragma unroll 2
    for (int t = 0; t < nb; ++t) {
      int e = __shfl(eL, t);
      int rt = __shfl(rL, t);
      int k2 = e >> LOG2_NV;
      const float* wcol = kernel_w + (k2 << 10) + (h << 4) * C_CH + c32;
      float psum = 0.f;
#pragma unroll
      for (int i = 0; i < 16; ++i)
        psum = fmaf(av[t & 1][i], wcol[i * C_CH], psum);
      if (t + 2 < nb) {                        // prefetch rows for t+2
        int e2 = __shfl(eL, t + 2);
        const float* arow = in_feature + ((e2 & 0x3FFFF) << 5) + (h << 4);
#pragma unroll
        for (int i = 0; i < 16; ++i) av[t & 1][i] = arow[i];
      }
      psum += __shfl_xor(psum, 32);
      if (h == 0) aux[wv][rt][c32] += psum;
    }
  }

  // ---- epilogue: C/D layout col=lane&15, row=quad*4+reg (m89/m91) ----
  float b0v = bias[r16], b1v = bias[16 + r16];
#pragma unroll
  for (int reg = 0; reg < 4; ++reg) {
    int row = quad * 4 + reg;
    float o0 = acc0[reg] + aux[wv][row][r16] + b0v;
    float o1 = acc1[reg] + aux[wv][row][16 + r16] + b1v;
    out[(vb + row) * C_CH + r16] = o0;
    out[(vb + row) * C_CH + 16 + r16] = o1;
  }
}

// ---------------------------------------------------------------------------
// Emergency finisher: the ~tens of entries that overflowed S2.
__global__ __launch_bounds__(BLOCK) void emergency_kernel(
    const float* __restrict__ in_feature, const float* __restrict__ kernel_w,
    const int* __restrict__ ecnt, const int2* __restrict__ elist,
    float* __restrict__ out) {
  int e = blockIdx.x * BLOCK + threadIdx.x;
  int n = *ecnt;
  if (n > ECAP) n = ECAP;
  if (e >= n) return;
  int2 ent = elist[e];
  int v = ent.x, k = ent.y >> LOG2_NV, in = ent.y & 0x3FFFF;
  float a[C_CH];
  const float4* ar = (const float4*)(in_feature + (in << 5));
#pragma unroll
  for (int q = 0; q < 8; ++q) ((float4*)a)[q] = ar[q];
  for (int c = 0; c < C_CH; ++c) {
    float s = 0.f;
#pragma unroll
    for (int i = 0; i < C_CH; ++i)
      s = fmaf(a[i], kernel_w[(k << 10) + i * C_CH + c], s);
    atomicAdd(&out[v * C_CH + c], s);
  }
}

// ---------------------------------------------------------------------------
// Fallback (tiny ws): round-1 direct-atomic version. Correct, slow.
__global__ __launch_bounds__(BLOCK) void init_bias_kernel(
    float* __restrict__ out, const float* __restrict__ bias, int n4) {
  int idx = blockIdx.x * blockDim.x + threadIdx.x;
  if (idx >= n4) return;
  ((float4*)out)[idx] = ((const float4*)bias)[idx & 7];
}

__global__ __launch_bounds__(BLOCK) void scatter_conv_kernel(
    const float* __restrict__ in_feature, const float* __restrict__ kernel_w,
    const int* __restrict__ nbmap, float* __restrict__ out) {
  const int k = blockIdx.x >> 9;
  const int pair = blockIdx.x * BLOCK + threadIdx.x;
  const float* __restrict__ Wk = kernel_w + k * (C_CH * C_CH);
  const int2 nb = ((const int2*)nbmap)[pair];
  const float4* __restrict__ inrow =
      (const float4*)(in_feature + (long)nb.x * C_CH);
  float a[C_CH];
#pragma unroll
  for (int j = 0; j < 8; ++j) ((float4*)a)[j] = inrow[j];
  float acc[C_CH];
#pragma unroll
  for (int c = 0; c < C_CH; ++c) acc[c] = 0.0f;
#pragma unroll
  for (int i = 0; i < C_CH; ++i) {
    const float av = a[i];
#pragma unroll
    for (int c = 0; c < C_CH; ++c)
      acc[c] = fmaf(av, Wk[i * C_CH + c], acc[c]);
  }
  float* __restrict__ orow = out + (long)nb.y * C_CH;
#pragma unroll
  for (int c = 0; c < C_CH; ++c) atomicAdd(orow + c, acc[c]);
}

// ===========================================================================
extern "C" void kernel_launch(void* const* d_in, const int* in_sizes, int n_in,
                              void* d_out, int out_size, void* d_ws,
                              size_t ws_size, hipStream_t stream) {
  const float* in_feature = (const float*)d_in[0];
  const float* kernel_w   = (const float*)d_in[1];
  const float* bias       = (const float*)d_in[2];
  const int*   nbmap      = (const int*)d_in[3];
  float* out = (float*)d_out;
  const int M = in_sizes[3] / 2;                 // 3,538,944

  // ws layout (ints): T[27*N] | ovf_cnt[N] | ecnt[64] | elist[8192]
  //                   | Bf[13824] | ovf[S2*N]
  const long FIXED = 64 + 2 * ECAP + 13824;
  long ws_ints = (long)(ws_size / 4);
  long s2_cap = (ws_ints - FIXED) / N_VOX - (K3 + 1);
  int S2 = (int)(s2_cap > 15 ? 15 : s2_cap);

  if (S2 < 4) {
    const int n4 = out_size / 4;
    init_bias_kernel<<<(n4 + BLOCK - 1) / BLOCK, BLOCK, 0, stream>>>(out, bias,
                                                                     n4);
    scatter_conv_kernel<<<M / BLOCK, BLOCK, 0, stream>>>(in_feature, kernel_w,
                                                         nbmap, out);
    return;
  }

  int* T        = (int*)d_ws;                       // [27][N_VOX]
  int* ovf_cnt  = T + (long)K3 * N_VOX;             // [N_VOX]
  int* ecnt     = ovf_cnt + N_VOX;                  // [64] (use [0])
  int2* elist   = (int2*)(ecnt + 64);               // [ECAP]
  unsigned short* Bf = (unsigned short*)(ecnt + 64 + 2 * ECAP);  // [27648]
  int* ovf      = (int*)(Bf + 2 * 13824);           // [S2][N_VOX]

  hipMemsetAsync(T, 0xFF, (size_t)K3 * N_VOX * 4, stream);
  hipMemsetAsync(ovf_cnt, 0, (size_t)(N_VOX + 64) * 4, stream);

  bf_prep_kernel<<<(K3 * 2 * 64 + BLOCK - 1) / BLOCK, BLOCK, 0, stream>>>(
      kernel_w, Bf);
  passA_kernel<<<M / BLOCK, BLOCK, 0, stream>>>((const int2*)nbmap, T, M);
  passB_kernel<<<M / BLOCK, BLOCK, 0, stream>>>((const int2*)nbmap, T,
                                                ovf_cnt, ovf, S2, ecnt, elist,
                                                M);
  gather_mfma_kernel<<<N_VOX / 64, BLOCK, 0, stream>>>(
      in_feature, kernel_w, bias, T, ovf_cnt, ovf, Bf, out, S2);
  emergency_kernel<<<ECAP / BLOCK, BLOCK, 0, stream>>>(in_feature, kernel_w,
                                                       ecnt, elist, out);
}